// Round 7
// baseline (113.522 us; speedup 1.0000x reference)
//
#include <hip/hip_runtime.h>

// hnode_prompt_layer_feature_cat_edge
// out[d, 0:128]   = (sum_{e: dst[e]=d} emb[src[e]]) * w
// out[d, 128:160] =  sum_{e: dst[e]=d} e_feat[e]
//
// R7: bucket CSR + gather with TWO NODES PER 32-LANE GROUP (4 nodes/wave):
//  - 4-deep unroll per node -> 16 emb + 4 e_feat loads in flight per wave
//    (2x R6), head chain (cursor->bucket->shfl) amortized over 2 nodes.
//  - branchless masked main loop: clamped convergent shfls + fma-mask
//    accumulate (no divergent tails, no inactive-source shfl UB).
//  - overflow drain folded into gather (node's own wave scans ovf list when
//    raw degree > CAP) -> one fewer dispatch, no store/atomic race.

#define D_FT 128
#define D_E 32
#define D_OUT (D_FT + D_E)
#define CAP 32

typedef float f32x4 __attribute__((ext_vector_type(4)));
typedef int   i32x2 __attribute__((ext_vector_type(2)));

__device__ __forceinline__ int clampi(int t, int hi) {
    t = t > hi ? hi : t;          // hi = cnt-1 (may be -1 when cnt==0)
    return t < 0 ? 0 : t;         // -> v_med3_i32-style clamp
}

__global__ void place_bucket_kernel(const int* __restrict__ src_idx,
                                    const int* __restrict__ dst_idx,
                                    int* __restrict__ cursor,
                                    i32x2* __restrict__ bucket,
                                    int* __restrict__ ovf,
                                    int* __restrict__ ovf_cnt, int E) {
    int i = blockIdx.x * blockDim.x + threadIdx.x;
    if (i >= E) return;
    int d = dst_idx[i];
    int slot = atomicAdd(&cursor[d], 1);
    if (slot < CAP) {
        i32x2 pr; pr.x = src_idx[i]; pr.y = i;
        __builtin_nontemporal_store(pr, &bucket[(size_t)d * CAP + slot]);
    } else {
        int p = atomicAdd(ovf_cnt, 1);
        ovf[p] = i;
    }
}

__global__ void gather_bucket_kernel(const float* __restrict__ emb,
                                     const float* __restrict__ e_feat,
                                     const float* __restrict__ w,
                                     const int* __restrict__ cursor,
                                     const i32x2* __restrict__ bucket,
                                     const int* __restrict__ src_idx,
                                     const int* __restrict__ dst_idx,
                                     const int* __restrict__ ovf,
                                     const int* __restrict__ ovf_cnt,
                                     float* __restrict__ out, int N) {
    int grp = (blockIdx.x * blockDim.x + threadIdx.x) >> 5;  // 32-lane group
    int ga = grp * 2;
    if (ga >= N) return;                   // group-uniform exit
    int gb = ga + 1;
    const int q  = threadIdx.x & 31;       // float4 slot in 128-wide row
    const int qg = q >> 3;                 // e_feat edge-subgroup 0..3
    const int ql = q & 7;                  // float4 slot in e_feat row

    // degrees (one 8B load covers both nodes; cursor[N..] is allocated)
    int2 cc = *reinterpret_cast<const int2*>(cursor + ga);
    int rawa = cc.x;
    int rawb = (gb < N) ? cc.y : 0;
    int cnta = rawa > CAP ? CAP : rawa;
    int cntb = rawb > CAP ? CAP : rawb;

    i32x2 pra; pra.x = 0; pra.y = 0;
    i32x2 prb; prb.x = 0; prb.y = 0;
    if (q < cnta) pra = __builtin_nontemporal_load(&bucket[(size_t)ga * CAP + q]);
    if (q < cntb) prb = __builtin_nontemporal_load(&bucket[(size_t)gb * CAP + q]);

    float4 fa = make_float4(0.f, 0.f, 0.f, 0.f);
    float4 fb = make_float4(0.f, 0.f, 0.f, 0.f);
    float4 ea = make_float4(0.f, 0.f, 0.f, 0.f);
    float4 eb = make_float4(0.f, 0.f, 0.f, 0.f);

    const int ca = cnta - 1, cb = cntb - 1;
    const int mx = cnta > cntb ? cnta : cntb;
    for (int i = 0; i < mx; i += 4) {
        // all shfls convergent: whole group executes, clamped source lanes
        int sa0 = __shfl(pra.x, clampi(i + 0, ca), 32);
        int sa1 = __shfl(pra.x, clampi(i + 1, ca), 32);
        int sa2 = __shfl(pra.x, clampi(i + 2, ca), 32);
        int sa3 = __shfl(pra.x, clampi(i + 3, ca), 32);
        int sb0 = __shfl(prb.x, clampi(i + 0, cb), 32);
        int sb1 = __shfl(prb.x, clampi(i + 1, cb), 32);
        int sb2 = __shfl(prb.x, clampi(i + 2, cb), 32);
        int sb3 = __shfl(prb.x, clampi(i + 3, cb), 32);
        int eia = __shfl(pra.y, clampi(i + qg, ca), 32);
        int eib = __shfl(prb.y, clampi(i + qg, cb), 32);

        float4 va0 = *reinterpret_cast<const float4*>(emb + (size_t)sa0 * D_FT + q * 4);
        float4 va1 = *reinterpret_cast<const float4*>(emb + (size_t)sa1 * D_FT + q * 4);
        float4 va2 = *reinterpret_cast<const float4*>(emb + (size_t)sa2 * D_FT + q * 4);
        float4 va3 = *reinterpret_cast<const float4*>(emb + (size_t)sa3 * D_FT + q * 4);
        float4 vb0 = *reinterpret_cast<const float4*>(emb + (size_t)sb0 * D_FT + q * 4);
        float4 vb1 = *reinterpret_cast<const float4*>(emb + (size_t)sb1 * D_FT + q * 4);
        float4 vb2 = *reinterpret_cast<const float4*>(emb + (size_t)sb2 * D_FT + q * 4);
        float4 vb3 = *reinterpret_cast<const float4*>(emb + (size_t)sb3 * D_FT + q * 4);
        f32x4 aea = __builtin_nontemporal_load(
            reinterpret_cast<const f32x4*>(e_feat + (size_t)eia * D_E + ql * 4));
        f32x4 aeb = __builtin_nontemporal_load(
            reinterpret_cast<const f32x4*>(e_feat + (size_t)eib * D_E + ql * 4));

        float ma0 = (i + 0 < cnta) ? 1.f : 0.f;
        float ma1 = (i + 1 < cnta) ? 1.f : 0.f;
        float ma2 = (i + 2 < cnta) ? 1.f : 0.f;
        float ma3 = (i + 3 < cnta) ? 1.f : 0.f;
        float mb0 = (i + 0 < cntb) ? 1.f : 0.f;
        float mb1 = (i + 1 < cntb) ? 1.f : 0.f;
        float mb2 = (i + 2 < cntb) ? 1.f : 0.f;
        float mb3 = (i + 3 < cntb) ? 1.f : 0.f;
        float mea = (i + qg < cnta) ? 1.f : 0.f;
        float meb = (i + qg < cntb) ? 1.f : 0.f;

        fa.x = fmaf(va0.x, ma0, fa.x); fa.y = fmaf(va0.y, ma0, fa.y);
        fa.z = fmaf(va0.z, ma0, fa.z); fa.w = fmaf(va0.w, ma0, fa.w);
        fa.x = fmaf(va1.x, ma1, fa.x); fa.y = fmaf(va1.y, ma1, fa.y);
        fa.z = fmaf(va1.z, ma1, fa.z); fa.w = fmaf(va1.w, ma1, fa.w);
        fa.x = fmaf(va2.x, ma2, fa.x); fa.y = fmaf(va2.y, ma2, fa.y);
        fa.z = fmaf(va2.z, ma2, fa.z); fa.w = fmaf(va2.w, ma2, fa.w);
        fa.x = fmaf(va3.x, ma3, fa.x); fa.y = fmaf(va3.y, ma3, fa.y);
        fa.z = fmaf(va3.z, ma3, fa.z); fa.w = fmaf(va3.w, ma3, fa.w);
        fb.x = fmaf(vb0.x, mb0, fb.x); fb.y = fmaf(vb0.y, mb0, fb.y);
        fb.z = fmaf(vb0.z, mb0, fb.z); fb.w = fmaf(vb0.w, mb0, fb.w);
        fb.x = fmaf(vb1.x, mb1, fb.x); fb.y = fmaf(vb1.y, mb1, fb.y);
        fb.z = fmaf(vb1.z, mb1, fb.z); fb.w = fmaf(vb1.w, mb1, fb.w);
        fb.x = fmaf(vb2.x, mb2, fb.x); fb.y = fmaf(vb2.y, mb2, fb.y);
        fb.z = fmaf(vb2.z, mb2, fb.z); fb.w = fmaf(vb2.w, mb2, fb.w);
        fb.x = fmaf(vb3.x, mb3, fb.x); fb.y = fmaf(vb3.y, mb3, fb.y);
        fb.z = fmaf(vb3.z, mb3, fb.z); fb.w = fmaf(vb3.w, mb3, fb.w);
        ea.x = fmaf(aea.x, mea, ea.x); ea.y = fmaf(aea.y, mea, ea.y);
        ea.z = fmaf(aea.z, mea, ea.z); ea.w = fmaf(aea.w, mea, ea.w);
        eb.x = fmaf(aeb.x, meb, eb.x); eb.y = fmaf(aeb.y, meb, eb.y);
        eb.z = fmaf(aeb.z, meb, eb.z); eb.w = fmaf(aeb.w, meb, eb.w);
    }

    // overflow edges (raw degree > CAP): node's own group drains them here,
    // so the final store below already includes them (no atomics, no race).
    if (rawa > CAP || rawb > CAP) {
        int n = *ovf_cnt;
        for (int k = 0; k < n; ++k) {
            int eid = ovf[k];
            int dd = dst_idx[eid];
            bool isa = (dd == ga), isb = (dd == gb);
            if (isa || isb) {
                int s = src_idx[eid];
                float4 v = *reinterpret_cast<const float4*>(emb + (size_t)s * D_FT + q * 4);
                f32x4 af = __builtin_nontemporal_load(
                    reinterpret_cast<const f32x4*>(e_feat + (size_t)eid * D_E + ql * 4));
                if (isa) {
                    fa.x += v.x; fa.y += v.y; fa.z += v.z; fa.w += v.w;
                    if (q < 8) { ea.x += af.x; ea.y += af.y; ea.z += af.z; ea.w += af.w; }
                } else {
                    fb.x += v.x; fb.y += v.y; fb.z += v.z; fb.w += v.w;
                    if (q < 8) { eb.x += af.x; eb.y += af.y; eb.z += af.z; eb.w += af.w; }
                }
            }
        }
    }

    // reduce e partials across the 4 edge-subgroups (convergent)
    ea.x += __shfl_xor(ea.x, 8, 32);  ea.y += __shfl_xor(ea.y, 8, 32);
    ea.z += __shfl_xor(ea.z, 8, 32);  ea.w += __shfl_xor(ea.w, 8, 32);
    ea.x += __shfl_xor(ea.x, 16, 32); ea.y += __shfl_xor(ea.y, 16, 32);
    ea.z += __shfl_xor(ea.z, 16, 32); ea.w += __shfl_xor(ea.w, 16, 32);
    eb.x += __shfl_xor(eb.x, 8, 32);  eb.y += __shfl_xor(eb.y, 8, 32);
    eb.z += __shfl_xor(eb.z, 8, 32);  eb.w += __shfl_xor(eb.w, 8, 32);
    eb.x += __shfl_xor(eb.x, 16, 32); eb.y += __shfl_xor(eb.y, 16, 32);
    eb.z += __shfl_xor(eb.z, 16, 32); eb.w += __shfl_xor(eb.w, 16, 32);

    float4 wv = *reinterpret_cast<const float4*>(w + q * 4);
    {
        float* oa = out + (size_t)ga * D_OUT;
        f32x4 r; r.x = fa.x * wv.x; r.y = fa.y * wv.y;
                 r.z = fa.z * wv.z; r.w = fa.w * wv.w;
        __builtin_nontemporal_store(r, reinterpret_cast<f32x4*>(oa + q * 4));
        if (q < 8) {
            f32x4 re; re.x = ea.x; re.y = ea.y; re.z = ea.z; re.w = ea.w;
            __builtin_nontemporal_store(re, reinterpret_cast<f32x4*>(oa + D_FT + q * 4));
        }
    }
    if (gb < N) {
        float* ob = out + (size_t)gb * D_OUT;
        f32x4 r; r.x = fb.x * wv.x; r.y = fb.y * wv.y;
                 r.z = fb.z * wv.z; r.w = fb.w * wv.w;
        __builtin_nontemporal_store(r, reinterpret_cast<f32x4*>(ob + q * 4));
        if (q < 8) {
            f32x4 re; re.x = eb.x; re.y = eb.y; re.z = eb.z; re.w = eb.w;
            __builtin_nontemporal_store(re, reinterpret_cast<f32x4*>(ob + D_FT + q * 4));
        }
    }
}

// ---- fallback (R1 atomic path) if ws too small ----
__global__ void scatter_ft_kernel(const float* __restrict__ emb, const float* __restrict__ w,
                                  const int* __restrict__ src_idx, const int* __restrict__ dst_idx,
                                  float* __restrict__ out, int n_items) {
    int idx = blockIdx.x * blockDim.x + threadIdx.x;
    if (idx >= n_items) return;
    int e = idx >> 5, q = idx & 31;
    int s = src_idx[e], d = dst_idx[e];
    const float4 v  = *reinterpret_cast<const float4*>(emb + (size_t)s * D_FT + q * 4);
    const float4 wv = *reinterpret_cast<const float4*>(w + q * 4);
    float* o = out + (size_t)d * D_OUT + q * 4;
    atomicAdd(o + 0, v.x * wv.x); atomicAdd(o + 1, v.y * wv.y);
    atomicAdd(o + 2, v.z * wv.z); atomicAdd(o + 3, v.w * wv.w);
}
__global__ void scatter_e_kernel(const float* __restrict__ e_feat, const int* __restrict__ dst_idx,
                                 float* __restrict__ out, int n_items) {
    int idx = blockIdx.x * blockDim.x + threadIdx.x;
    if (idx >= n_items) return;
    int e = idx >> 3, q = idx & 7;
    int d = dst_idx[e];
    const float4 v = *reinterpret_cast<const float4*>(e_feat + (size_t)e * D_E + q * 4);
    float* o = out + (size_t)d * D_OUT + D_FT + q * 4;
    atomicAdd(o + 0, v.x); atomicAdd(o + 1, v.y);
    atomicAdd(o + 2, v.z); atomicAdd(o + 3, v.w);
}

extern "C" void kernel_launch(void* const* d_in, const int* in_sizes, int n_in,
                              void* d_out, int out_size, void* d_ws, size_t ws_size,
                              hipStream_t stream) {
    const float* emb    = (const float*)d_in[0];   // [N, 128]
    const float* e_feat = (const float*)d_in[1];   // [E, 32]
    const float* w      = (const float*)d_in[2];   // [1, 128]
    const int*   src    = (const int*)d_in[3];     // [E]
    const int*   dst    = (const int*)d_in[4];     // [E]
    float* out = (float*)d_out;                    // [N, 160]

    const int E = in_sizes[3];
    const int N = out_size / D_OUT;

    // ws layout: cursor[N] | ovf_cnt[1] | pad[1] | bucket[N*CAP] i32x2 | ovf[E]
    size_t ints_head = (size_t)N + 2;
    size_t need = ints_head * 4 + (size_t)N * CAP * 8 + (size_t)E * 4;

    if (ws_size >= need) {
        int*   cursor  = (int*)d_ws;
        int*   ovf_cnt = cursor + N;
        i32x2* bucket  = (i32x2*)(cursor + ints_head);
        int*   ovf     = (int*)(bucket + (size_t)N * CAP);

        hipMemsetAsync(cursor, 0, ints_head * sizeof(int), stream);
        place_bucket_kernel<<<(E + 255) / 256, 256, 0, stream>>>(
            src, dst, cursor, bucket, ovf, ovf_cnt, E);
        int groups = (N + 1) / 2;   // 2 nodes per 32-lane group
        gather_bucket_kernel<<<((size_t)groups * 32 + 255) / 256, 256, 0, stream>>>(
            emb, e_feat, w, cursor, bucket, src, dst, ovf, ovf_cnt, out, N);
    } else {
        hipMemsetAsync(d_out, 0, (size_t)out_size * sizeof(float), stream);
        int items_ft = E * 32, items_e = E * 8;
        scatter_ft_kernel<<<(items_ft + 255) / 256, 256, 0, stream>>>(emb, w, src, dst, out, items_ft);
        scatter_e_kernel<<<(items_e + 255) / 256, 256, 0, stream>>>(e_feat, dst, out, items_e);
    }
}

// Round 8
// 107.499 us; speedup vs baseline: 1.0560x; 1.0560x over previous
//
#include <hip/hip_runtime.h>

// hnode_prompt_layer_feature_cat_edge
// out[d, 0:128]   = (sum_{e: dst[e]=d} emb[src[e]]) * w
// out[d, 128:160] =  sum_{e: dst[e]=d} e_feat[e]
//
// R8 = R6 gather (proven best: 28 VGPR, 70% occ) with ONE dependency fix:
//  - bucket row loaded UNCONDITIONALLY (lane&31) so it issues in parallel
//    with the cursor load (head chain was cursor -> bucket -> shfl -> emb).
//    Safety: no consumed shfl source ever reaches a slot >= cnt (main-loop
//    sources b+qg <= i+7 <= cnt-1; tails clamp source AND guard the load),
//    so stale bucket data is never used as an index.
//  - place: 2 edges/thread, int2 vector loads, two independent atomic->store
//    chains (2x MLP on the latency-bound CSR build), nt stores.
//  - ovf drain stays a separate tiny dispatch (don't perturb gather regalloc).

#define D_FT 128
#define D_E 32
#define D_OUT (D_FT + D_E)
#define CAP 32

typedef float f32x4 __attribute__((ext_vector_type(4)));
typedef int   i32x2 __attribute__((ext_vector_type(2)));

__global__ void place_bucket_kernel(const int* __restrict__ src_idx,
                                    const int* __restrict__ dst_idx,
                                    int* __restrict__ cursor,
                                    i32x2* __restrict__ bucket,
                                    int* __restrict__ ovf,
                                    int* __restrict__ ovf_cnt, int E) {
    int i = blockIdx.x * blockDim.x + threadIdx.x;
    int e0 = i * 2;
    if (e0 >= E) return;
    bool two = (e0 + 1 < E);
    int2 d2, s2;
    if (two) {
        d2 = *reinterpret_cast<const int2*>(dst_idx + e0);
        s2 = *reinterpret_cast<const int2*>(src_idx + e0);
    } else {
        d2.x = dst_idx[e0]; d2.y = 0;
        s2.x = src_idx[e0]; s2.y = 0;
    }
    // two independent atomic chains
    int slot0 = atomicAdd(&cursor[d2.x], 1);
    int slot1 = two ? atomicAdd(&cursor[d2.y], 1) : CAP;
    if (slot0 < CAP) {
        i32x2 pr; pr.x = s2.x; pr.y = e0;
        __builtin_nontemporal_store(pr, &bucket[(size_t)d2.x * CAP + slot0]);
    } else {
        int p = atomicAdd(ovf_cnt, 1);
        ovf[p] = e0;
    }
    if (two) {
        if (slot1 < CAP) {
            i32x2 pr; pr.x = s2.y; pr.y = e0 + 1;
            __builtin_nontemporal_store(pr, &bucket[(size_t)d2.y * CAP + slot1]);
        } else {
            int p = atomicAdd(ovf_cnt, 1);
            ovf[p] = e0 + 1;
        }
    }
}

__global__ void gather_bucket_kernel(const float* __restrict__ emb,
                                     const float* __restrict__ e_feat,
                                     const float* __restrict__ w,
                                     const int* __restrict__ cursor,
                                     const i32x2* __restrict__ bucket,
                                     float* __restrict__ out, int N) {
    int g = (blockIdx.x * blockDim.x + threadIdx.x) >> 6;   // node = one wave
    if (g >= N) return;                                     // wave-uniform exit
    const int lane = threadIdx.x & 63;
    const int half = lane >> 5;      // 0/1: which 4-edge slice of the 8/iter
    const int q    = lane & 31;      // float4 slot within the 128-wide row
    const int qg   = q >> 3;         // e_feat edge-subgroup 0..3 within half
    const int ql   = q & 7;          // float4 slot within e_feat row

    // cursor load and bucket load issue INDEPENDENTLY (no guard on bucket).
    // Lanes 32-63 read the same 256B row as lanes 0-31 (broadcast); slots
    // >= cnt hold stale data but are never consumed (see clamps below).
    i32x2 pr = __builtin_nontemporal_load(&bucket[(size_t)g * CAP + (lane & 31)]);
    int cnt = cursor[g];
    cnt = cnt > CAP ? CAP : cnt;

    float4 accft = make_float4(0.f, 0.f, 0.f, 0.f);
    float4 acce  = make_float4(0.f, 0.f, 0.f, 0.f);  // partial for (half,qg)

    int i = 0;
    for (; i + 8 <= cnt; i += 8) {
        // convergent shfls: sources b..b+3, b+qg <= i+7 <= cnt-1 are valid
        int b  = i + (half << 2);
        int s0 = __shfl(pr.x, b + 0, 64);
        int s1 = __shfl(pr.x, b + 1, 64);
        int s2 = __shfl(pr.x, b + 2, 64);
        int s3 = __shfl(pr.x, b + 3, 64);
        int ee = __shfl(pr.y, b + qg, 64);
        float4 v0 = *reinterpret_cast<const float4*>(emb + (size_t)s0 * D_FT + q * 4);
        float4 v1 = *reinterpret_cast<const float4*>(emb + (size_t)s1 * D_FT + q * 4);
        float4 v2 = *reinterpret_cast<const float4*>(emb + (size_t)s2 * D_FT + q * 4);
        float4 v3 = *reinterpret_cast<const float4*>(emb + (size_t)s3 * D_FT + q * 4);
        f32x4 a = __builtin_nontemporal_load(
            reinterpret_cast<const f32x4*>(e_feat + (size_t)ee * D_E + ql * 4));
        accft.x += (v0.x + v1.x) + (v2.x + v3.x);
        accft.y += (v0.y + v1.y) + (v2.y + v3.y);
        accft.z += (v0.z + v1.z) + (v2.z + v3.z);
        accft.w += (v0.w + v1.w) + (v2.w + v3.w);
        acce.x += a.x; acce.y += a.y; acce.z += a.z; acce.w += a.w;
    }
    // e_feat tail: r = cnt - i in [0,7], one shot across 8 lane-groups.
    // shfl OUTSIDE the guard, clamped source (active, valid lane); load guarded.
    {
        int t = i + (half << 2) + qg;
        int tsrc = (t < cnt) ? t : 0;
        int ee = __shfl(pr.y, tsrc, 64);
        if (t < cnt) {
            f32x4 a = __builtin_nontemporal_load(
                reinterpret_cast<const f32x4*>(e_feat + (size_t)ee * D_E + ql * 4));
            acce.x += a.x; acce.y += a.y; acce.z += a.z; acce.w += a.w;
        }
    }
    // emb tail: halves split odd/even; loop bounds uniform, shfl unguarded.
    for (int j = i; j < cnt; j += 2) {
        int t = j + half;
        int tsrc = (t < cnt) ? t : 0;
        int s = __shfl(pr.x, tsrc, 64);
        if (t < cnt) {
            float4 v = *reinterpret_cast<const float4*>(emb + (size_t)s * D_FT + q * 4);
            accft.x += v.x; accft.y += v.y; accft.z += v.z; accft.w += v.w;
        }
    }

    // combine the two halves' ft partials
    accft.x += __shfl_xor(accft.x, 32, 64);
    accft.y += __shfl_xor(accft.y, 32, 64);
    accft.z += __shfl_xor(accft.z, 32, 64);
    accft.w += __shfl_xor(accft.w, 32, 64);
    // combine e partials: across qg (8,16) then across halves (32)
    acce.x += __shfl_xor(acce.x, 8, 64);
    acce.y += __shfl_xor(acce.y, 8, 64);
    acce.z += __shfl_xor(acce.z, 8, 64);
    acce.w += __shfl_xor(acce.w, 8, 64);
    acce.x += __shfl_xor(acce.x, 16, 64);
    acce.y += __shfl_xor(acce.y, 16, 64);
    acce.z += __shfl_xor(acce.z, 16, 64);
    acce.w += __shfl_xor(acce.w, 16, 64);
    acce.x += __shfl_xor(acce.x, 32, 64);
    acce.y += __shfl_xor(acce.y, 32, 64);
    acce.z += __shfl_xor(acce.z, 32, 64);
    acce.w += __shfl_xor(acce.w, 32, 64);

    if (half == 0) {
        float4 wv = *reinterpret_cast<const float4*>(w + q * 4);
        float* o = out + (size_t)g * D_OUT;
        f32x4 r; r.x = accft.x * wv.x; r.y = accft.y * wv.y;
                 r.z = accft.z * wv.z; r.w = accft.w * wv.w;
        __builtin_nontemporal_store(r, reinterpret_cast<f32x4*>(o + q * 4));
        if (q < 8) {
            f32x4 re; re.x = acce.x; re.y = acce.y; re.z = acce.z; re.w = acce.w;
            __builtin_nontemporal_store(re, reinterpret_cast<f32x4*>(o + D_FT + q * 4));
        }
    }
}

// Drain overflow edges (deg > CAP; ~never fires for this data, correct always).
__global__ void ovf_scatter_kernel(const float* __restrict__ emb,
                                   const float* __restrict__ e_feat,
                                   const float* __restrict__ w,
                                   const int* __restrict__ src_idx,
                                   const int* __restrict__ dst_idx,
                                   const int* __restrict__ ovf,
                                   const int* __restrict__ ovf_cnt,
                                   float* __restrict__ out) {
    int n = *ovf_cnt;
    int total = n * 40;   // 32 ft float4-slots + 8 e float4-slots per edge
    for (int t = blockIdx.x * blockDim.x + threadIdx.x; t < total;
         t += gridDim.x * blockDim.x) {
        int e = t / 40, slot = t % 40;
        int eid = ovf[e];
        int d = dst_idx[eid];
        float* o = out + (size_t)d * D_OUT;
        if (slot < 32) {
            int s = src_idx[eid];
            float4 v  = *reinterpret_cast<const float4*>(emb + (size_t)s * D_FT + slot * 4);
            float4 wv = *reinterpret_cast<const float4*>(w + slot * 4);
            atomicAdd(o + slot * 4 + 0, v.x * wv.x);
            atomicAdd(o + slot * 4 + 1, v.y * wv.y);
            atomicAdd(o + slot * 4 + 2, v.z * wv.z);
            atomicAdd(o + slot * 4 + 3, v.w * wv.w);
        } else {
            int qq = slot - 32;
            float4 ve = *reinterpret_cast<const float4*>(e_feat + (size_t)eid * D_E + qq * 4);
            atomicAdd(o + D_FT + qq * 4 + 0, ve.x);
            atomicAdd(o + D_FT + qq * 4 + 1, ve.y);
            atomicAdd(o + D_FT + qq * 4 + 2, ve.z);
            atomicAdd(o + D_FT + qq * 4 + 3, ve.w);
        }
    }
}

// ---- fallback (R1 atomic path) if ws too small ----
__global__ void scatter_ft_kernel(const float* __restrict__ emb, const float* __restrict__ w,
                                  const int* __restrict__ src_idx, const int* __restrict__ dst_idx,
                                  float* __restrict__ out, int n_items) {
    int idx = blockIdx.x * blockDim.x + threadIdx.x;
    if (idx >= n_items) return;
    int e = idx >> 5, q = idx & 31;
    int s = src_idx[e], d = dst_idx[e];
    const float4 v  = *reinterpret_cast<const float4*>(emb + (size_t)s * D_FT + q * 4);
    const float4 wv = *reinterpret_cast<const float4*>(w + q * 4);
    float* o = out + (size_t)d * D_OUT + q * 4;
    atomicAdd(o + 0, v.x * wv.x); atomicAdd(o + 1, v.y * wv.y);
    atomicAdd(o + 2, v.z * wv.z); atomicAdd(o + 3, v.w * wv.w);
}
__global__ void scatter_e_kernel(const float* __restrict__ e_feat, const int* __restrict__ dst_idx,
                                 float* __restrict__ out, int n_items) {
    int idx = blockIdx.x * blockDim.x + threadIdx.x;
    if (idx >= n_items) return;
    int e = idx >> 3, q = idx & 7;
    int d = dst_idx[e];
    const float4 v = *reinterpret_cast<const float4*>(e_feat + (size_t)e * D_E + q * 4);
    float* o = out + (size_t)d * D_OUT + D_FT + q * 4;
    atomicAdd(o + 0, v.x); atomicAdd(o + 1, v.y);
    atomicAdd(o + 2, v.z); atomicAdd(o + 3, v.w);
}

extern "C" void kernel_launch(void* const* d_in, const int* in_sizes, int n_in,
                              void* d_out, int out_size, void* d_ws, size_t ws_size,
                              hipStream_t stream) {
    const float* emb    = (const float*)d_in[0];   // [N, 128]
    const float* e_feat = (const float*)d_in[1];   // [E, 32]
    const float* w      = (const float*)d_in[2];   // [1, 128]
    const int*   src    = (const int*)d_in[3];     // [E]
    const int*   dst    = (const int*)d_in[4];     // [E]
    float* out = (float*)d_out;                    // [N, 160]

    const int E = in_sizes[3];
    const int N = out_size / D_OUT;

    // ws layout: cursor[N] | ovf_cnt[1] | pad[1] | bucket[N*CAP] i32x2 | ovf[E]
    size_t ints_head = (size_t)N + 2;
    size_t need = ints_head * 4 + (size_t)N * CAP * 8 + (size_t)E * 4;

    if (ws_size >= need) {
        int*   cursor  = (int*)d_ws;
        int*   ovf_cnt = cursor + N;
        i32x2* bucket  = (i32x2*)(cursor + ints_head);
        int*   ovf     = (int*)(bucket + (size_t)N * CAP);

        hipMemsetAsync(cursor, 0, ints_head * sizeof(int), stream);
        int pthreads = (E + 1) / 2;   // 2 edges per thread
        place_bucket_kernel<<<(pthreads + 255) / 256, 256, 0, stream>>>(
            src, dst, cursor, bucket, ovf, ovf_cnt, E);
        gather_bucket_kernel<<<((size_t)N * 64 + 255) / 256, 256, 0, stream>>>(
            emb, e_feat, w, cursor, bucket, out, N);
        ovf_scatter_kernel<<<128, 256, 0, stream>>>(
            emb, e_feat, w, src, dst, ovf, ovf_cnt, out);
    } else {
        hipMemsetAsync(d_out, 0, (size_t)out_size * sizeof(float), stream);
        int items_ft = E * 32, items_e = E * 8;
        scatter_ft_kernel<<<(items_ft + 255) / 256, 256, 0, stream>>>(emb, w, src, dst, out, items_ft);
        scatter_e_kernel<<<(items_e + 255) / 256, 256, 0, stream>>>(e_feat, dst, out, items_e);
    }
}

// Round 9
// 100.964 us; speedup vs baseline: 1.1244x; 1.0647x over previous
//
#include <hip/hip_runtime.h>

// hnode_prompt_layer_feature_cat_edge
// out[d, 0:128]   = (sum_{e: dst[e]=d} emb[src[e]]) * w
// out[d, 128:160] =  sum_{e: dst[e]=d} e_feat[e]
//
// R9 = R8 gather + masked full-width tail block; place reverted to R6's
// 1-edge/thread (R8's 2-edge place cost ~5us of TLP on the atomic chain).
//  - main loop: unmasked 8-edge blocks while i+8 <= cnt.
//  - remainder: ONE masked 8-edge block — clamped convergent shfls (sources
//    always valid active lanes), clamped redundant loads (L1-hit), fma-mask
//    accumulate. Keeps 8 emb loads in flight for the remainder edges, which
//    dominate at deg~Poisson(12). No divergent tails, no inactive-lane shfl.

#define D_FT 128
#define D_E 32
#define D_OUT (D_FT + D_E)
#define CAP 32

typedef float f32x4 __attribute__((ext_vector_type(4)));
typedef int   i32x2 __attribute__((ext_vector_type(2)));

__global__ void place_bucket_kernel(const int* __restrict__ src_idx,
                                    const int* __restrict__ dst_idx,
                                    int* __restrict__ cursor,
                                    i32x2* __restrict__ bucket,
                                    int* __restrict__ ovf,
                                    int* __restrict__ ovf_cnt, int E) {
    int i = blockIdx.x * blockDim.x + threadIdx.x;
    if (i >= E) return;
    int d = dst_idx[i];
    int slot = atomicAdd(&cursor[d], 1);
    if (slot < CAP) {
        i32x2 pr; pr.x = src_idx[i]; pr.y = i;
        bucket[(size_t)d * CAP + slot] = pr;
    } else {
        int p = atomicAdd(ovf_cnt, 1);
        ovf[p] = i;
    }
}

__global__ void gather_bucket_kernel(const float* __restrict__ emb,
                                     const float* __restrict__ e_feat,
                                     const float* __restrict__ w,
                                     const int* __restrict__ cursor,
                                     const i32x2* __restrict__ bucket,
                                     float* __restrict__ out, int N) {
    int g = (blockIdx.x * blockDim.x + threadIdx.x) >> 6;   // node = one wave
    if (g >= N) return;                                     // wave-uniform exit
    const int lane = threadIdx.x & 63;
    const int half = lane >> 5;      // 0/1: which 4-edge slice of the 8/iter
    const int q    = lane & 31;      // float4 slot within the 128-wide row
    const int qg   = q >> 3;         // e_feat edge-subgroup 0..3 within half
    const int ql   = q & 7;          // float4 slot within e_feat row

    // cursor load and bucket load issue INDEPENDENTLY (no guard on bucket).
    // Slots >= cnt hold stale data but are never consumed as indices without
    // clamping, and clamped-redundant loads only touch valid rows.
    i32x2 pr = __builtin_nontemporal_load(&bucket[(size_t)g * CAP + (lane & 31)]);
    int cnt = cursor[g];
    cnt = cnt > CAP ? CAP : cnt;

    float4 accft = make_float4(0.f, 0.f, 0.f, 0.f);
    float4 acce  = make_float4(0.f, 0.f, 0.f, 0.f);  // partial for (half,qg)

    int i = 0;
    for (; i + 8 <= cnt; i += 8) {
        // convergent shfls: sources b..b+3, b+qg <= i+7 <= cnt-1 are valid
        int b  = i + (half << 2);
        int s0 = __shfl(pr.x, b + 0, 64);
        int s1 = __shfl(pr.x, b + 1, 64);
        int s2 = __shfl(pr.x, b + 2, 64);
        int s3 = __shfl(pr.x, b + 3, 64);
        int ee = __shfl(pr.y, b + qg, 64);
        float4 v0 = *reinterpret_cast<const float4*>(emb + (size_t)s0 * D_FT + q * 4);
        float4 v1 = *reinterpret_cast<const float4*>(emb + (size_t)s1 * D_FT + q * 4);
        float4 v2 = *reinterpret_cast<const float4*>(emb + (size_t)s2 * D_FT + q * 4);
        float4 v3 = *reinterpret_cast<const float4*>(emb + (size_t)s3 * D_FT + q * 4);
        f32x4 a = __builtin_nontemporal_load(
            reinterpret_cast<const f32x4*>(e_feat + (size_t)ee * D_E + ql * 4));
        accft.x += (v0.x + v1.x) + (v2.x + v3.x);
        accft.y += (v0.y + v1.y) + (v2.y + v3.y);
        accft.z += (v0.z + v1.z) + (v2.z + v3.z);
        accft.w += (v0.w + v1.w) + (v2.w + v3.w);
        acce.x += a.x; acce.y += a.y; acce.z += a.z; acce.w += a.w;
    }
    // Remainder (cnt - i in [1,7] when taken): ONE masked full-width block.
    // Group-uniform entry; shfl sources clamped to [0, cnt-1] (valid, active
    // lanes); loads use clamped indices (redundant -> same line, L1-hit);
    // fma masks zero the redundant contributions.
    if (i < cnt) {
        const int c1 = cnt - 1;
        int b  = i + (half << 2);
        int t0 = b + 0, t1 = b + 1, t2 = b + 2, t3 = b + 3, te = b + qg;
        int s0 = __shfl(pr.x, t0 < c1 ? t0 : c1, 64);
        int s1 = __shfl(pr.x, t1 < c1 ? t1 : c1, 64);
        int s2 = __shfl(pr.x, t2 < c1 ? t2 : c1, 64);
        int s3 = __shfl(pr.x, t3 < c1 ? t3 : c1, 64);
        int ee = __shfl(pr.y, te < c1 ? te : c1, 64);
        float4 v0 = *reinterpret_cast<const float4*>(emb + (size_t)s0 * D_FT + q * 4);
        float4 v1 = *reinterpret_cast<const float4*>(emb + (size_t)s1 * D_FT + q * 4);
        float4 v2 = *reinterpret_cast<const float4*>(emb + (size_t)s2 * D_FT + q * 4);
        float4 v3 = *reinterpret_cast<const float4*>(emb + (size_t)s3 * D_FT + q * 4);
        f32x4 a = __builtin_nontemporal_load(
            reinterpret_cast<const f32x4*>(e_feat + (size_t)ee * D_E + ql * 4));
        float m0 = (t0 < cnt) ? 1.f : 0.f;
        float m1 = (t1 < cnt) ? 1.f : 0.f;
        float m2 = (t2 < cnt) ? 1.f : 0.f;
        float m3 = (t3 < cnt) ? 1.f : 0.f;
        float me = (te < cnt) ? 1.f : 0.f;
        accft.x = fmaf(v0.x, m0, accft.x); accft.y = fmaf(v0.y, m0, accft.y);
        accft.z = fmaf(v0.z, m0, accft.z); accft.w = fmaf(v0.w, m0, accft.w);
        accft.x = fmaf(v1.x, m1, accft.x); accft.y = fmaf(v1.y, m1, accft.y);
        accft.z = fmaf(v1.z, m1, accft.z); accft.w = fmaf(v1.w, m1, accft.w);
        accft.x = fmaf(v2.x, m2, accft.x); accft.y = fmaf(v2.y, m2, accft.y);
        accft.z = fmaf(v2.z, m2, accft.z); accft.w = fmaf(v2.w, m2, accft.w);
        accft.x = fmaf(v3.x, m3, accft.x); accft.y = fmaf(v3.y, m3, accft.y);
        accft.z = fmaf(v3.z, m3, accft.z); accft.w = fmaf(v3.w, m3, accft.w);
        acce.x = fmaf(a.x, me, acce.x); acce.y = fmaf(a.y, me, acce.y);
        acce.z = fmaf(a.z, me, acce.z); acce.w = fmaf(a.w, me, acce.w);
    }

    // combine the two halves' ft partials
    accft.x += __shfl_xor(accft.x, 32, 64);
    accft.y += __shfl_xor(accft.y, 32, 64);
    accft.z += __shfl_xor(accft.z, 32, 64);
    accft.w += __shfl_xor(accft.w, 32, 64);
    // combine e partials: across qg (8,16) then across halves (32)
    acce.x += __shfl_xor(acce.x, 8, 64);
    acce.y += __shfl_xor(acce.y, 8, 64);
    acce.z += __shfl_xor(acce.z, 8, 64);
    acce.w += __shfl_xor(acce.w, 8, 64);
    acce.x += __shfl_xor(acce.x, 16, 64);
    acce.y += __shfl_xor(acce.y, 16, 64);
    acce.z += __shfl_xor(acce.z, 16, 64);
    acce.w += __shfl_xor(acce.w, 16, 64);
    acce.x += __shfl_xor(acce.x, 32, 64);
    acce.y += __shfl_xor(acce.y, 32, 64);
    acce.z += __shfl_xor(acce.z, 32, 64);
    acce.w += __shfl_xor(acce.w, 32, 64);

    if (half == 0) {
        float4 wv = *reinterpret_cast<const float4*>(w + q * 4);
        float* o = out + (size_t)g * D_OUT;
        f32x4 r; r.x = accft.x * wv.x; r.y = accft.y * wv.y;
                 r.z = accft.z * wv.z; r.w = accft.w * wv.w;
        __builtin_nontemporal_store(r, reinterpret_cast<f32x4*>(o + q * 4));
        if (q < 8) {
            f32x4 re; re.x = acce.x; re.y = acce.y; re.z = acce.z; re.w = acce.w;
            __builtin_nontemporal_store(re, reinterpret_cast<f32x4*>(o + D_FT + q * 4));
        }
    }
}

// Drain overflow edges (deg > CAP; ~never fires for this data, correct always).
__global__ void ovf_scatter_kernel(const float* __restrict__ emb,
                                   const float* __restrict__ e_feat,
                                   const float* __restrict__ w,
                                   const int* __restrict__ src_idx,
                                   const int* __restrict__ dst_idx,
                                   const int* __restrict__ ovf,
                                   const int* __restrict__ ovf_cnt,
                                   float* __restrict__ out) {
    int n = *ovf_cnt;
    int total = n * 40;   // 32 ft float4-slots + 8 e float4-slots per edge
    for (int t = blockIdx.x * blockDim.x + threadIdx.x; t < total;
         t += gridDim.x * blockDim.x) {
        int e = t / 40, slot = t % 40;
        int eid = ovf[e];
        int d = dst_idx[eid];
        float* o = out + (size_t)d * D_OUT;
        if (slot < 32) {
            int s = src_idx[eid];
            float4 v  = *reinterpret_cast<const float4*>(emb + (size_t)s * D_FT + slot * 4);
            float4 wv = *reinterpret_cast<const float4*>(w + slot * 4);
            atomicAdd(o + slot * 4 + 0, v.x * wv.x);
            atomicAdd(o + slot * 4 + 1, v.y * wv.y);
            atomicAdd(o + slot * 4 + 2, v.z * wv.z);
            atomicAdd(o + slot * 4 + 3, v.w * wv.w);
        } else {
            int qq = slot - 32;
            float4 ve = *reinterpret_cast<const float4*>(e_feat + (size_t)eid * D_E + qq * 4);
            atomicAdd(o + D_FT + qq * 4 + 0, ve.x);
            atomicAdd(o + D_FT + qq * 4 + 1, ve.y);
            atomicAdd(o + D_FT + qq * 4 + 2, ve.z);
            atomicAdd(o + D_FT + qq * 4 + 3, ve.w);
        }
    }
}

// ---- fallback (R1 atomic path) if ws too small ----
__global__ void scatter_ft_kernel(const float* __restrict__ emb, const float* __restrict__ w,
                                  const int* __restrict__ src_idx, const int* __restrict__ dst_idx,
                                  float* __restrict__ out, int n_items) {
    int idx = blockIdx.x * blockDim.x + threadIdx.x;
    if (idx >= n_items) return;
    int e = idx >> 5, q = idx & 31;
    int s = src_idx[e], d = dst_idx[e];
    const float4 v  = *reinterpret_cast<const float4*>(emb + (size_t)s * D_FT + q * 4);
    const float4 wv = *reinterpret_cast<const float4*>(w + q * 4);
    float* o = out + (size_t)d * D_OUT + q * 4;
    atomicAdd(o + 0, v.x * wv.x); atomicAdd(o + 1, v.y * wv.y);
    atomicAdd(o + 2, v.z * wv.z); atomicAdd(o + 3, v.w * wv.w);
}
__global__ void scatter_e_kernel(const float* __restrict__ e_feat, const int* __restrict__ dst_idx,
                                 float* __restrict__ out, int n_items) {
    int idx = blockIdx.x * blockDim.x + threadIdx.x;
    if (idx >= n_items) return;
    int e = idx >> 3, q = idx & 7;
    int d = dst_idx[e];
    const float4 v = *reinterpret_cast<const float4*>(e_feat + (size_t)e * D_E + q * 4);
    float* o = out + (size_t)d * D_OUT + D_FT + q * 4;
    atomicAdd(o + 0, v.x); atomicAdd(o + 1, v.y);
    atomicAdd(o + 2, v.z); atomicAdd(o + 3, v.w);
}

extern "C" void kernel_launch(void* const* d_in, const int* in_sizes, int n_in,
                              void* d_out, int out_size, void* d_ws, size_t ws_size,
                              hipStream_t stream) {
    const float* emb    = (const float*)d_in[0];   // [N, 128]
    const float* e_feat = (const float*)d_in[1];   // [E, 32]
    const float* w      = (const float*)d_in[2];   // [1, 128]
    const int*   src    = (const int*)d_in[3];     // [E]
    const int*   dst    = (const int*)d_in[4];     // [E]
    float* out = (float*)d_out;                    // [N, 160]

    const int E = in_sizes[3];
    const int N = out_size / D_OUT;

    // ws layout: cursor[N] | ovf_cnt[1] | pad[1] | bucket[N*CAP] i32x2 | ovf[E]
    size_t ints_head = (size_t)N + 2;
    size_t need = ints_head * 4 + (size_t)N * CAP * 8 + (size_t)E * 4;

    if (ws_size >= need) {
        int*   cursor  = (int*)d_ws;
        int*   ovf_cnt = cursor + N;
        i32x2* bucket  = (i32x2*)(cursor + ints_head);
        int*   ovf     = (int*)(bucket + (size_t)N * CAP);

        hipMemsetAsync(cursor, 0, ints_head * sizeof(int), stream);
        place_bucket_kernel<<<(E + 255) / 256, 256, 0, stream>>>(
            src, dst, cursor, bucket, ovf, ovf_cnt, E);
        gather_bucket_kernel<<<((size_t)N * 64 + 255) / 256, 256, 0, stream>>>(
            emb, e_feat, w, cursor, bucket, out, N);
        ovf_scatter_kernel<<<128, 256, 0, stream>>>(
            emb, e_feat, w, src, dst, ovf, ovf_cnt, out);
    } else {
        hipMemsetAsync(d_out, 0, (size_t)out_size * sizeof(float), stream);
        int items_ft = E * 32, items_e = E * 8;
        scatter_ft_kernel<<<(items_ft + 255) / 256, 256, 0, stream>>>(emb, w, src, dst, out, items_ft);
        scatter_e_kernel<<<(items_e + 255) / 256, 256, 0, stream>>>(e_feat, dst, out, items_e);
    }
}